// Round 13
// baseline (256.561 us; speedup 1.0000x reference)
//
#include <hip/hip_runtime.h>
#include <math.h>

#define N_NODES 10000
#define N_EDGES 320000
#define IN_FEATS 512
#define N_UNITS 256
#define OUT_FEATS 64
#define N_HID 5  // hidden Wh layers

typedef __attribute__((ext_vector_type(8))) short bf16x8;
typedef __attribute__((ext_vector_type(4))) float f32x4;

__device__ __forceinline__ unsigned short f2bf(float f) {
    union { float f; unsigned int u; } c; c.f = f;
    unsigned int u = c.u + 0x7FFFu + ((c.u >> 16) & 1u);  // RNE
    return (unsigned short)(u >> 16);
}
__device__ __forceinline__ float bf2f(unsigned int b) {
    union { unsigned int u; float f; } c; c.u = (b & 0xffffu) << 16;
    return c.f;
}

// ---------------- setup: deg histogram + weights->bf16 transposed (h stays fp32) ----------------

__global__ void k_setup(const int* __restrict__ dst, int* __restrict__ deg,
                        const float* __restrict__ W0, const float* __restrict__ Wh,
                        const float* __restrict__ Wo,
                        unsigned short* __restrict__ W0t, unsigned short* __restrict__ Wht,
                        unsigned short* __restrict__ Wot) {
    const int R1 = N_EDGES;
    const int S0 = IN_FEATS * N_UNITS;
    const int SH = N_HID * N_UNITS * N_UNITS;
    const int SO = N_UNITS * OUT_FEATS;
    int t = blockIdx.x * blockDim.x + threadIdx.x;
    if (t < R1) {
        atomicAdd(&deg[dst[t]], 1);
    } else {
        int u = t - R1;
        if (u < S0) {
            int k = u >> 8, n = u & 255;
            W0t[(size_t)n * IN_FEATS + k] = f2bf(W0[u]);
        } else if (u < S0 + SH) {
            int w = u - S0;
            int l = w >> 16, r = w & 65535;
            int k = r >> 8, n = r & 255;
            Wht[(size_t)l * 65536 + (size_t)n * N_UNITS + k] = f2bf(Wh[w]);
        } else if (u < S0 + SH + SO) {
            int w = u - S0 - SH;
            int k = w >> 6, n = w & 63;
            Wot[(size_t)n * N_UNITS + k] = f2bf(Wo[w]);
        }
    }
}

// ---------------- scan: one 1024-thread block, 10/thread, 3 barriers ----------------

__global__ __launch_bounds__(1024) void k_scan(const int* __restrict__ deg,
                                               int* __restrict__ row_ptr,
                                               int* __restrict__ cursor,
                                               float* __restrict__ dinv,
                                               float* __restrict__ invdeg) {
    __shared__ int wsum[16];
    const int PER = 10;
    int t = threadIdx.x;
    int lane = t & 63, wid = t >> 6;
    int base = t * PER;

    int v[PER];
    int s = 0;
#pragma unroll
    for (int j = 0; j < PER; ++j) {
        int i = base + j;
        int d = (i < N_NODES) ? deg[i] : 0;
        v[j] = s;
        s += d;
    }
    int inc = s;
#pragma unroll
    for (int off = 1; off < 64; off <<= 1) {
        int y = __shfl_up(inc, off);
        if (lane >= off) inc += y;
    }
    if (lane == 63) wsum[wid] = inc;
    __syncthreads();
    if (wid == 0) {
        int w = (lane < 16) ? wsum[lane] : 0;
#pragma unroll
        for (int off = 1; off < 16; off <<= 1) {
            int y = __shfl_up(w, off);
            if (lane >= off) w += y;
        }
        if (lane < 16) wsum[lane] = w;
    }
    __syncthreads();
    int wave_excl = (wid == 0) ? 0 : wsum[wid - 1];
    int thread_excl = wave_excl + (inc - s);

#pragma unroll
    for (int j = 0; j < PER; ++j) {
        int i = base + j;
        if (i < N_NODES) {
            int rp = thread_excl + v[j];
            row_ptr[i] = rp;
            cursor[i]  = rp;
            int d = ((j + 1 < PER) ? v[j + 1] : s) - v[j];
            float dd = (float)(d + 1);
            dinv[i]   = rsqrtf(dd);
            invdeg[i] = 1.0f / dd;
        }
    }
    if (t == 1023) row_ptr[N_NODES] = thread_excl + s;
}

__global__ void k_fill(const int* __restrict__ src, const int* __restrict__ dst,
                       int* __restrict__ cursor, int* __restrict__ csr_src) {
    int e = blockIdx.x * blockDim.x + threadIdx.x;
    if (e < N_EDGES) {
        int p = atomicAdd(&cursor[dst[e]], 1);
        csr_src[p] = src[e];
    }
}

// ---------------- layer-0 GEMM: m = h(fp32) @ W0t^T, BN=256 single pass over A ----------------
// 157 blocks; A read once as fp32, converted to bf16 in-reg during staging (reg->LDS,
// XOR-swizzled write+read pair); B double-buffered via global_load_lds (src-swizzled).

__global__ __launch_bounds__(256) void k_mgemm_h(const float* __restrict__ h,
                                                 const unsigned short* __restrict__ Bt,
                                                 unsigned short* __restrict__ C) {
    constexpr int K = IN_FEATS;   // 512
    constexpr int BM = 64, BN = 256, BK = 32;
    __shared__ unsigned short As[2 * BM * BK];   //  8 KB  (256 uint4 per buffer)
    __shared__ unsigned short Bs[2 * BN * BK];   // 32 KB  (1024 uint4 per buffer)

    const int tid  = threadIdx.x;
    const int wid  = tid >> 6;
    const int lane = tid & 63;
    const int wr   = wid >> 1;      // 0..1 row half
    const int wc   = wid & 1;       // 0..1 col half (128 cols each)
    const int brow = blockIdx.x * BM;

    const int lr = lane & 15;
    const int lk = lane >> 4;

    // A staging mapping: thread -> (row 0..63, seg 0..3 of 8 floats)
    const int arow = tid >> 2;
    const int aseg = tid & 3;
    const int asl  = aseg ^ ((arow >> 1) & 3);   // swizzled 16B slot (write side)
    int gra = brow + arow; if (gra >= N_NODES) gra = N_NODES - 1;
    const float* ap = h + (size_t)gra * K + aseg * 8;

    f32x4 acc[2][8];
#pragma unroll
    for (int m = 0; m < 2; ++m)
#pragma unroll
        for (int n = 0; n < 8; ++n)
            acc[m][n] = (f32x4){0.f, 0.f, 0.f, 0.f};

    // stage A: fp32 load -> bf16 pack -> swizzled LDS write
    // NOTE: buffer stride is 256 uint4 (BM*BK shorts = 4096 B). R12 bug was *512 here.
#define STAGE_A(buf, k0)                                                        \
    do {                                                                        \
        float4 v0 = *reinterpret_cast<const float4*>(ap + (k0));                \
        float4 v1 = *reinterpret_cast<const float4*>(ap + (k0) + 4);            \
        uint4 o;                                                                \
        o.x = f2bf(v0.x) | ((unsigned)f2bf(v0.y) << 16);                        \
        o.y = f2bf(v0.z) | ((unsigned)f2bf(v0.w) << 16);                        \
        o.z = f2bf(v1.x) | ((unsigned)f2bf(v1.y) << 16);                        \
        o.w = f2bf(v1.z) | ((unsigned)f2bf(v1.w) << 16);                        \
        ((uint4*)As)[(buf) * 256 + arow * 4 + asl] = o;                         \
    } while (0)

    // stage B: 256 rows x 4 slots = 1024 ops / 256 thr = 4 per thread
#define STAGE_B(buf, k0)                                                                     \
    do {                                                                                     \
        _Pragma("unroll")                                                                    \
        for (int p = 0; p < 4; ++p) {                                                        \
            int i2 = p * 256 + tid;                                                          \
            int row = i2 >> 2, sx = i2 & 3;                                                  \
            const unsigned short* gp =                                                       \
                Bt + (size_t)row * K + (k0) + ((sx ^ ((row >> 1) & 3)) * 8);                 \
            __builtin_amdgcn_global_load_lds(                                                \
                (const __attribute__((address_space(1))) void*)gp,                           \
                (__attribute__((address_space(3))) void*)(Bs + (buf) * BN * BK + i2 * 8),    \
                16, 0, 0);                                                                   \
        }                                                                                    \
    } while (0)

    STAGE_A(0, 0);
    STAGE_B(0, 0);
    __syncthreads();

    const int nk = K / BK;  // 16
    for (int kt = 0; kt < nk; ++kt) {
        const int cur = kt & 1;
        if (kt + 1 < nk) {
            STAGE_A(cur ^ 1, (kt + 1) * BK);
            STAGE_B(cur ^ 1, (kt + 1) * BK);
        }

        bf16x8 af[2], bfr[8];
#pragma unroll
        for (int m = 0; m < 2; ++m) {
            int ra = wr * 32 + m * 16 + lr;
            af[m] = *reinterpret_cast<const bf16x8*>(&As[cur * BM * BK + ra * BK + (lk ^ ((ra >> 1) & 3)) * 8]);
        }
#pragma unroll
        for (int n = 0; n < 8; ++n) {
            int rb = wc * 128 + n * 16 + lr;
            bfr[n] = *reinterpret_cast<const bf16x8*>(&Bs[cur * BN * BK + rb * BK + (lk ^ ((rb >> 1) & 3)) * 8]);
        }
#pragma unroll
        for (int m = 0; m < 2; ++m)
#pragma unroll
            for (int n = 0; n < 8; ++n)
                acc[m][n] = __builtin_amdgcn_mfma_f32_16x16x32_bf16(af[m], bfr[n], acc[m][n], 0, 0, 0);
        __syncthreads();
    }
#undef STAGE_A
#undef STAGE_B

#pragma unroll
    for (int m = 0; m < 2; ++m) {
#pragma unroll
        for (int r = 0; r < 4; ++r) {
            int orow = brow + wr * 32 + m * 16 + lk * 4 + r;
            if (orow < N_NODES) {
#pragma unroll
                for (int n = 0; n < 8; ++n) {
                    int ocol = wc * 128 + n * 16 + lr;
                    C[(size_t)orow * N_UNITS + ocol] = f2bf(acc[m][n][r]);
                }
            }
        }
    }
}

// ---------------- weight-stationary GEMM (K=256): full-K in LDS, ONE barrier ----------------

__global__ __launch_bounds__(256) void k_wgemm(const unsigned short* __restrict__ A,
                                               const unsigned short* __restrict__ Bt,
                                               unsigned short* __restrict__ C,
                                               const int M, const int Nld) {
    constexpr int K = 256;
    __shared__ unsigned short As[64 * K];
    __shared__ unsigned short Bs[64 * K];

    const int tid  = threadIdx.x;
    const int wid  = tid >> 6;
    const int lane = tid & 63;
    const int lr   = lane & 15;
    const int lk   = lane >> 4;
    const int brow = blockIdx.y * 64;
    const int bcol = blockIdx.x * 64;

#pragma unroll
    for (int p = 0; p < 8; ++p) {
        int i = p * 256 + tid;
        int row = i >> 5, s = i & 31;
        int gr = brow + row; if (gr >= M) gr = M - 1;
        const unsigned short* gp = A + (size_t)gr * K + ((s ^ (row & 7)) * 8);
        __builtin_amdgcn_global_load_lds(
            (const __attribute__((address_space(1))) void*)gp,
            (__attribute__((address_space(3))) void*)(As + i * 8), 16, 0, 0);
    }
#pragma unroll
    for (int p = 0; p < 8; ++p) {
        int i = p * 256 + tid;
        int row = i >> 5, s = i & 31;
        const unsigned short* gp = Bt + (size_t)(bcol + row) * K + ((s ^ (row & 7)) * 8);
        __builtin_amdgcn_global_load_lds(
            (const __attribute__((address_space(1))) void*)gp,
            (__attribute__((address_space(3))) void*)(Bs + i * 8), 16, 0, 0);
    }
    __syncthreads();

    f32x4 acc[4];
#pragma unroll
    for (int n = 0; n < 4; ++n) acc[n] = (f32x4){0.f, 0.f, 0.f, 0.f};

    const int ra = (wid << 4) + lr;
    const unsigned short* Arow = As + ra * K;
    const int e = lr & 7;
#pragma unroll
    for (int kk = 0; kk < 8; ++kk) {
        bf16x8 av = *reinterpret_cast<const bf16x8*>(&Arow[(((kk << 2) + lk) ^ e) * 8]);
#pragma unroll
        for (int n = 0; n < 4; ++n) {
            const unsigned short* Brow = Bs + ((n << 4) + lr) * K;
            bf16x8 bv = *reinterpret_cast<const bf16x8*>(&Brow[(((kk << 2) + lk) ^ e) * 8]);
            acc[n] = __builtin_amdgcn_mfma_f32_16x16x32_bf16(av, bv, acc[n], 0, 0, 0);
        }
    }

#pragma unroll
    for (int n = 0; n < 4; ++n) {
#pragma unroll
        for (int r = 0; r < 4; ++r) {
            int orow = brow + (wid << 4) + (lk << 2) + r;
            if (orow < M) {
                int ocol = bcol + (n << 4) + lr;
                C[(size_t)orow * Nld + ocol] = f2bf(acc[n][r]);
            }
        }
    }
}

// ---------------- CSR aggregation + bias + relu + running JK max ----------------
// 8 nodes / 256-thread block, 32 lanes/node, uint4/lane; UNROLL-8 with index prefetch.
// write_x=0 on the last hidden layer (x never read again; only jk survives).

__global__ __launch_bounds__(256) void k_agg(const unsigned short* __restrict__ m,
                                             const int* __restrict__ row_ptr,
                                             const int* __restrict__ csr_src,
                                             const float* __restrict__ bias,
                                             unsigned short* __restrict__ x_out,
                                             unsigned short* __restrict__ jk,
                                             int init_jk, int write_x) {
    int half = threadIdx.x >> 5;
    int lane = threadIdx.x & 31;
    int n = blockIdx.x * 8 + half;
    int s = row_ptr[n], e = row_ptr[n + 1];
    const uint4* mv = (const uint4*)m;

    float a[8];
#pragma unroll
    for (int j = 0; j < 8; ++j) a[j] = 0.f;

#define ACC8(u)                                        \
    do {                                               \
        a[0] += bf2f((u).x); a[1] += bf2f((u).x >> 16);\
        a[2] += bf2f((u).y); a[3] += bf2f((u).y >> 16);\
        a[4] += bf2f((u).z); a[5] += bf2f((u).z >> 16);\
        a[6] += bf2f((u).w); a[7] += bf2f((u).w >> 16);\
    } while (0)

    int i = s;
    for (; i + 7 < e; i += 8) {
        int idx[8];
#pragma unroll
        for (int q = 0; q < 8; ++q) idx[q] = csr_src[i + q];
        uint4 u[8];
#pragma unroll
        for (int q = 0; q < 8; ++q) u[q] = mv[(size_t)idx[q] * 32 + lane];
#pragma unroll
        for (int q = 0; q < 8; ++q) ACC8(u[q]);
    }
    for (; i < e; ++i) {
        uint4 u = mv[(size_t)csr_src[i] * 32 + lane];
        ACC8(u);
    }
#undef ACC8

    float4 b0 = ((const float4*)bias)[lane * 2];
    float4 b1 = ((const float4*)bias)[lane * 2 + 1];
    unsigned int hh[8];
    hh[0] = f2bf(fmaxf(a[0] + b0.x, 0.f));
    hh[1] = f2bf(fmaxf(a[1] + b0.y, 0.f));
    hh[2] = f2bf(fmaxf(a[2] + b0.z, 0.f));
    hh[3] = f2bf(fmaxf(a[3] + b0.w, 0.f));
    hh[4] = f2bf(fmaxf(a[4] + b1.x, 0.f));
    hh[5] = f2bf(fmaxf(a[5] + b1.y, 0.f));
    hh[6] = f2bf(fmaxf(a[6] + b1.z, 0.f));
    hh[7] = f2bf(fmaxf(a[7] + b1.w, 0.f));
    uint4 o;
    o.x = hh[0] | (hh[1] << 16);
    o.y = hh[2] | (hh[3] << 16);
    o.z = hh[4] | (hh[5] << 16);
    o.w = hh[6] | (hh[7] << 16);

    size_t idx = (size_t)n * 32 + lane;
    if (write_x) ((uint4*)x_out)[idx] = o;
    if (init_jk) {
        ((uint4*)jk)[idx] = o;
    } else {
        uint4 j = ((const uint4*)jk)[idx];
        auto mx2 = [](unsigned int nw, unsigned int od) {
            unsigned int lo_n = nw & 0xffffu, lo_o = od & 0xffffu;
            unsigned int hi_n = nw >> 16,     hi_o = od >> 16;
            unsigned int lo = lo_n > lo_o ? lo_n : lo_o;
            unsigned int hi = hi_n > hi_o ? hi_n : hi_o;
            return lo | (hi << 16);
        };
        uint4 w;
        w.x = mx2(o.x, j.x); w.y = mx2(o.y, j.y);
        w.z = mx2(o.z, j.z); w.w = mx2(o.w, j.w);
        ((uint4*)jk)[idx] = w;
    }
}

// ---------------- final GCN-norm agg + self loop + bias + log_softmax ----------------

__global__ __launch_bounds__(256) void k_final(const unsigned short* __restrict__ mf,
                                               const int* __restrict__ row_ptr,
                                               const int* __restrict__ csr_src,
                                               const float* __restrict__ dinv,
                                               const float* __restrict__ invdeg,
                                               const float* __restrict__ bo,
                                               float* __restrict__ out) {
    int halfw = threadIdx.x >> 5;
    int wl = threadIdx.x & 31;
    const unsigned int* mfu = (const unsigned int*)mf;
    int n = blockIdx.x * 8 + halfw;
    int s = row_ptr[n], e = row_ptr[n + 1];

    float a0 = 0.f, a1 = 0.f;
    int i = s;
    for (; i + 3 < e; i += 4) {
        int i0 = csr_src[i], i1 = csr_src[i + 1], i2 = csr_src[i + 2], i3 = csr_src[i + 3];
        unsigned int u0 = mfu[(size_t)i0 * 32 + wl];
        unsigned int u1 = mfu[(size_t)i1 * 32 + wl];
        unsigned int u2 = mfu[(size_t)i2 * 32 + wl];
        unsigned int u3 = mfu[(size_t)i3 * 32 + wl];
        float d0 = dinv[i0], d1 = dinv[i1], d2 = dinv[i2], d3 = dinv[i3];
        a0 += bf2f(u0) * d0 + bf2f(u1) * d1 + bf2f(u2) * d2 + bf2f(u3) * d3;
        a1 += bf2f(u0 >> 16) * d0 + bf2f(u1 >> 16) * d1 + bf2f(u2 >> 16) * d2 + bf2f(u3 >> 16) * d3;
    }
    for (; i < e; ++i) {
        int sr = csr_src[i];
        unsigned int u = mfu[(size_t)sr * 32 + wl];
        float dv = dinv[sr];
        a0 += bf2f(u) * dv;
        a1 += bf2f(u >> 16) * dv;
    }
    float dn = dinv[n];
    a0 *= dn; a1 *= dn;
    unsigned int un = mfu[(size_t)n * 32 + wl];
    float idg = invdeg[n];
    float2 bo2 = ((const float2*)bo)[wl];
    a0 += bf2f(un) * idg + bo2.x;
    a1 += bf2f(un >> 16) * idg + bo2.y;

    float mx = fmaxf(a0, a1);
#pragma unroll
    for (int off = 16; off; off >>= 1) mx = fmaxf(mx, __shfl_xor(mx, off));
    float e0 = __expf(a0 - mx), e1 = __expf(a1 - mx);
    float sum = e0 + e1;
#pragma unroll
    for (int off = 16; off; off >>= 1) sum += __shfl_xor(sum, off);
    float ls = __logf(sum);
    float2 r;
    r.x = a0 - mx - ls;
    r.y = a1 - mx - ls;
    ((float2*)out)[(size_t)n * 32 + wl] = r;
}

// ---------------- launch ----------------

extern "C" void kernel_launch(void* const* d_in, const int* in_sizes, int n_in,
                              void* d_out, int out_size, void* d_ws, size_t ws_size,
                              hipStream_t stream) {
    const float* h  = (const float*)d_in[0];
    const int*   ei = (const int*)d_in[1];
    const float* W0 = (const float*)d_in[2];
    const float* b0 = (const float*)d_in[3];
    const float* Wh = (const float*)d_in[4];
    const float* bh = (const float*)d_in[5];
    const float* Wo = (const float*)d_in[6];
    const float* bo = (const float*)d_in[7];

    const int* src = ei;
    const int* dst = ei + N_EDGES;

    char* p = (char*)d_ws;
    auto carve = [&](size_t bytes) {
        char* r = p;
        p += (bytes + 255) & ~(size_t)255;
        return r;
    };
    int*   deg     = (int*)  carve(N_NODES * 4);
    int*   row_ptr = (int*)  carve((N_NODES + 1) * 4);
    int*   cursor  = (int*)  carve(N_NODES * 4);
    int*   csr_src = (int*)  carve(N_EDGES * 4);
    float* dinv    = (float*)carve(N_NODES * 4);
    float* invdeg  = (float*)carve(N_NODES * 4);
    unsigned short* W0t = (unsigned short*)carve((size_t)IN_FEATS * N_UNITS * 2);
    unsigned short* Wht = (unsigned short*)carve((size_t)N_HID * N_UNITS * N_UNITS * 2);
    unsigned short* Wot = (unsigned short*)carve((size_t)N_UNITS * OUT_FEATS * 2);
    unsigned short* m   = (unsigned short*)carve((size_t)N_NODES * N_UNITS * 2);
    unsigned short* x   = (unsigned short*)carve((size_t)N_NODES * N_UNITS * 2);
    unsigned short* jk  = (unsigned short*)carve((size_t)N_NODES * N_UNITS * 2);
    unsigned short* mf  = (unsigned short*)carve((size_t)N_NODES * OUT_FEATS * 2);

    hipMemsetAsync(deg, 0, N_NODES * 4, stream);
    {
        const int total = N_EDGES +
                          IN_FEATS * N_UNITS + N_HID * N_UNITS * N_UNITS + N_UNITS * OUT_FEATS;
        k_setup<<<(total + 255) / 256, 256, 0, stream>>>(dst, deg, W0, Wh, Wo,
                                                         W0t, Wht, Wot);
    }
    k_scan<<<1, 1024, 0, stream>>>(deg, row_ptr, cursor, dinv, invdeg);
    k_fill<<<(N_EDGES + 255) / 256, 256, 0, stream>>>(src, dst, cursor, csr_src);

    const int GBM = (N_NODES + 63) / 64;  // 157

    // layer 0: m = h(fp32) @ W0t^T, single pass over A
    k_mgemm_h<<<GBM, 256, 0, stream>>>(h, W0t, m);
    k_agg<<<N_NODES / 8, 256, 0, stream>>>(m, row_ptr, csr_src, b0, x, jk, 1, 1);

    // hidden layers: weight-stationary K=256
    for (int l = 0; l < N_HID; ++l) {
        dim3 g(N_UNITS / 64, GBM);
        k_wgemm<<<g, 256, 0, stream>>>(x, Wht + (size_t)l * N_UNITS * N_UNITS, m,
                                       N_NODES, N_UNITS);
        k_agg<<<N_NODES / 8, 256, 0, stream>>>(m, row_ptr, csr_src, bh + (size_t)l * N_UNITS,
                                               x, jk, 0, (l < N_HID - 1) ? 1 : 0);
    }

    // final: mf = jk @ Wot^T (K=256, N=64)
    {
        dim3 g(1, GBM);
        k_wgemm<<<g, 256, 0, stream>>>(jk, Wot, mf, N_NODES, OUT_FEATS);
    }
    k_final<<<N_NODES / 8, 256, 0, stream>>>(mf, row_ptr, csr_src, dinv, invdeg,
                                             bo, (float*)d_out);
}